// Round 8
// baseline (397.242 us; speedup 1.0000x reference)
//
#include <hip/hip_runtime.h>
#include <hip/hip_bf16.h>

// ELSA block. Inputs: float32. Output: float32. Internal: bf16 (MFMA) + f16 (conv).
// Pipeline:
//  k_prep: weight repack (interleave q/k rows, pad, fold ghost, dup conv w as f16 (w,w))
//  k_ln:   LayerNorm, x (B,C,D,H,W) f32 -> xn_t (frame*pix, 96) bf16 [pixel-major]
//  k_gemm<0>: qkv projection (MFMA) -> h=(q*k*scale) (f,c,p) f16, v (f,c,p) bf16
//  k_conv: grouped 7x7 conv + exact GELU via v_pk_fma_f16 (SGPR weight op) -> a_t BLOCKED-4
//  2 chunks of 8 frames:  k_gemm<1>: 294-ch logits + ghost -> attn_c (8f,294,p)
//                         k_aggr: 49-tap window aggregation -> out_t BLOCKED-4
//                                 (XCD-swizzled: 4 cquads of a head co-resident)
//  k_gemm<2>: out proj + bias + f32 residual -> d_out f32 (B,C,D,H,W)
// Workspace (bytes), total 128,512,512 (~122.6 MB):
//  [0)        W2 (320x96 bf16)  61,440
//  [61440)    bias2 (320 f32)    1,280
//  [62720)    WA2 (320x96 bf16) 61,440
//  [124160)   biasA2 (320 f32)   1,280
//  [125440)   WP (128x96 bf16)  24,576
//  [150016)   biasP (128 f32)      512
//  [150528)   WCV (24x4x7x4x7 uint dup-f16) 75,264
//  [225792)   xn_t / a_t   28,311,552
//  [28537344) h / out_t    28,311,552
//  [56848896) v            28,311,552
//  [85160448) attn_c (8x294x9216 bf16) 43,352,064

typedef unsigned short u16;
typedef short bf16x8 __attribute__((ext_vector_type(8)));
typedef float floatx4 __attribute__((ext_vector_type(4)));
typedef unsigned short ushort8 __attribute__((ext_vector_type(8)));
typedef unsigned int uint4v __attribute__((ext_vector_type(4)));
typedef unsigned int uint2v __attribute__((ext_vector_type(2)));
typedef _Float16 f16x2 __attribute__((ext_vector_type(2)));

#define PIX      9216
#define SCALE_QK 0.25f

__device__ __forceinline__ float lo2f(unsigned int u) {
  union { unsigned int i; float f; } z; z.i = u << 16; return z.f;
}
__device__ __forceinline__ float hi2f(unsigned int u) {
  union { unsigned int i; float f; } z; z.i = u & 0xFFFF0000u; return z.f;
}
__device__ __forceinline__ u16 f2b(float f) {
  union { float f; unsigned int i; } z; z.f = f;
  unsigned int r = z.i + 0x7fffu + ((z.i >> 16) & 1u);
  return (u16)(r >> 16);
}
__device__ __forceinline__ u16 f2h(float f) {
  _Float16 h = (_Float16)f;
  union { _Float16 h; u16 u; } z; z.h = h; return z.u;
}
__device__ __forceinline__ f16x2 upk(unsigned int u) {
  union { unsigned int u; f16x2 h; } z; z.u = u; return z.h;
}
// Packed f16 FMA with the wave-uniform weight in an SGPR (VOP3P allows one
// SGPR source). Avoids R5's failure mode (weights forced to VGPR, mov flood)
// while guaranteeing 2 MACs per VALU slot (R4/R6 builtin form scalarized).
__device__ __forceinline__ unsigned int pkfma_s(unsigned int w, unsigned int x,
                                                unsigned int c) {
  unsigned int d;
  asm("v_pk_fma_f16 %0, %1, %2, %3" : "=v"(d) : "s"(w), "v"(x), "v"(c));
  return d;
}

// ---------------- weight prep (f32 in, bf16/f16/f32 out) ----------------
__global__ void k_prep(const float* __restrict__ w_qk, const float* __restrict__ b_qk,
                       const float* __restrict__ w_v,  const float* __restrict__ b_v,
                       const float* __restrict__ w_a1,
                       const float* __restrict__ w_a2, const float* __restrict__ b_a2,
                       const float* __restrict__ g_mul,const float* __restrict__ g_add,
                       const float* __restrict__ w_p,  const float* __restrict__ b_p,
                       u16* __restrict__ W2, float* __restrict__ bias2,
                       u16* __restrict__ WA2, float* __restrict__ biasA2,
                       u16* __restrict__ WP, float* __restrict__ biasP,
                       unsigned int* __restrict__ WCV) {
  int i = blockIdx.x * 256 + threadIdx.x;
  if (i < 30720) {                       // W2: 320*96
    int r = i / 96, ci = i % 96;
    float val = 0.f;
    if (r < 192) { int src = (r & 1) ? (96 + (r >> 1)) : (r >> 1); val = w_qk[src * 96 + ci]; }
    else if (r < 288) val = w_v[(r - 192) * 96 + ci];
    W2[i] = f2b(val);
  } else if (i < 31040) {                // bias2: 320
    int r = i - 30720; float bv = 0.f;
    if (r < 192) { int src = (r & 1) ? (96 + (r >> 1)) : (r >> 1); bv = b_qk[src]; }
    else if (r < 288) bv = b_v[r - 192];
    bias2[r] = bv;
  } else if (i < 61760) {                // WA2: 320*96
    int j = i - 31040; int r = j / 96, ci = j % 96;
    float wv = 0.f;
    if (r < 294) wv = w_a2[r * 96 + ci] * g_mul[r];
    WA2[j] = f2b(wv);
  } else if (i < 62080) {                // biasA2: 320
    int r = i - 61760; float bv = 0.f;
    if (r < 294) bv = b_a2[r] * g_mul[r] + g_add[r];
    biasA2[r] = bv;
  } else if (i < 74368) {                // WP: 128*96
    int j = i - 62080; int r = j / 96;
    WP[j] = (r < 96) ? f2b(w_p[j]) : (u16)0;
  } else if (i < 74496) {                // biasP: 128
    int r = i - 74368;
    biasP[r] = (r < 96) ? b_p[r] : 0.f;
  } else if (i < 93312) {                // WCV: dup f16 [g][ch][ky][co][kx], 18816 uints
    int j = i - 74496;
    int kx = j % 7, co = (j / 7) & 3, ky = (j / 28) % 7, ch = (j / 196) & 3, g = j / 784;
    float w = w_a1[(g * 4 + co) * 196 + ch * 49 + ky * 7 + kx];
    unsigned int hw = f2h(w);
    WCV[j] = hw | (hw << 16);
  }
}

// ---------------- LayerNorm ----------------
__global__ __launch_bounds__(256) void k_ln(const float* __restrict__ x,
                                            const float* __restrict__ lg,
                                            const float* __restrict__ lb,
                                            u16* __restrict__ xn) {
  int idx = blockIdx.x * 256 + threadIdx.x;    // 0..147455
  int f = idx / PIX, p = idx % PIX;
  int b = f >> 3, d = f & 7;
  size_t base = ((size_t)(b * 768 + d)) * PIX + p;  // + c*73728
  float s = 0.f, ss = 0.f;
  for (int c = 0; c < 96; ++c) {
    float v = x[base + (size_t)c * 73728];
    s += v; ss += v * v;
  }
  float mu = s * (1.f / 96.f);
  float var = ss * (1.f / 96.f) - mu * mu;
  float rs = rsqrtf(var + 1e-5f);
  size_t ob = (size_t)idx * 96;
  for (int c0 = 0; c0 < 96; c0 += 8) {
    ushort8 pack;
    for (int u = 0; u < 8; ++u) {
      int c = c0 + u;
      float v = x[base + (size_t)c * 73728];
      pack[u] = f2b((v - mu) * rs * lg[c] + lb[c]);
    }
    *(ushort8*)&xn[ob + c0] = pack;
  }
}

// ---------------- MFMA GEMM (64co x 64p tile, K=96) ----------------
// MODE 0: qkv -> h f16 (out0), v bf16 (out1), f = blockIdx.z. X = xn_t.
// MODE 1: attn chunk (out0, f = fArg + blockIdx.z, store frame-local z). X = a_t BLOCKED-4.
// MODE 2: final f32 (outF = d_out), resid = x f32, f = blockIdx.z. X = out_t BLOCKED-4.
template <int MODE>
__global__ __launch_bounds__(256) void k_gemm(const u16* __restrict__ X,
                                              const u16* __restrict__ W,
                                              const float* __restrict__ bias,
                                              u16* __restrict__ out0,
                                              u16* __restrict__ out1,
                                              float* __restrict__ outF,
                                              const float* __restrict__ resid,
                                              int fArg) {
  __shared__ u16 lw[64 * 104];
  __shared__ u16 lx[64 * 104];
  const int tid = threadIdx.x;
  const int fc = blockIdx.z;
  const int f = (MODE == 1) ? (fArg + fc) : fc;
  const int p0 = blockIdx.x * 64;
  const int cot = blockIdx.y;

  if constexpr (MODE == 0) {
    for (int ch = tid; ch < 768; ch += 256) {
      int r = ch / 12, s2 = ch % 12;
      *(uint4v*)&lw[r * 104 + s2 * 8] = *(const uint4v*)&W[(size_t)(cot * 64 + r) * 96 + s2 * 8];
      *(uint4v*)&lx[r * 104 + s2 * 8] = *(const uint4v*)&X[((size_t)(f * PIX + p0 + r)) * 96 + s2 * 8];
    }
  } else {
    for (int ch = tid; ch < 768; ch += 256) {
      int r = ch / 12, s2 = ch % 12;
      *(uint4v*)&lw[r * 104 + s2 * 8] = *(const uint4v*)&W[(size_t)(cot * 64 + r) * 96 + s2 * 8];
    }
    // X is blocked-4: X[((f*24 + g)*PIX + p)*4 + co]. Channel-oct s2 spans
    // groups 2*s2, 2*s2+1. r fastest across lanes -> contiguous 8B reads.
    for (int idx = tid; idx < 768; idx += 256) {
      int s2 = idx >> 6, r = idx & 63;
      const u16* src0 = &X[((size_t)(f * 24 + 2 * s2) * PIX + p0 + r) * 4];
      const u16* src1 = &X[((size_t)(f * 24 + 2 * s2 + 1) * PIX + p0 + r) * 4];
      *(uint2v*)&lx[r * 104 + s2 * 8]     = *(const uint2v*)src0;
      *(uint2v*)&lx[r * 104 + s2 * 8 + 4] = *(const uint2v*)src1;
    }
  }
  __syncthreads();

  const int lane = tid & 63, wv = tid >> 6;
  const int cw = (wv >> 1) * 32, pw = (wv & 1) * 32;
  const int m = lane & 15, quad = lane >> 4;

  floatx4 acc[2][2] = {};
  for (int ks = 0; ks < 3; ++ks) {
    int ko = ks * 32 + quad * 8;
    bf16x8 a0 = *(const bf16x8*)&lw[(cw + m) * 104 + ko];
    bf16x8 a1 = *(const bf16x8*)&lw[(cw + 16 + m) * 104 + ko];
    bf16x8 b0 = *(const bf16x8*)&lx[(pw + m) * 104 + ko];
    bf16x8 b1 = *(const bf16x8*)&lx[(pw + 16 + m) * 104 + ko];
    acc[0][0] = __builtin_amdgcn_mfma_f32_16x16x32_bf16(a0, b0, acc[0][0], 0, 0, 0);
    acc[0][1] = __builtin_amdgcn_mfma_f32_16x16x32_bf16(a0, b1, acc[0][1], 0, 0, 0);
    acc[1][0] = __builtin_amdgcn_mfma_f32_16x16x32_bf16(a1, b0, acc[1][0], 0, 0, 0);
    acc[1][1] = __builtin_amdgcn_mfma_f32_16x16x32_bf16(a1, b1, acc[1][1], 0, 0, 0);
  }

  for (int mt = 0; mt < 2; ++mt)
    for (int nt = 0; nt < 2; ++nt) {
      int R = cot * 64 + cw + mt * 16 + quad * 4;
      int pc = p0 + pw + nt * 16 + m;
      floatx4 v4 = acc[mt][nt];
      if (MODE == 0) {
        if (cot < 3) {
          float q0 = v4[0] + bias[R + 0], k0 = v4[1] + bias[R + 1];
          float q1 = v4[2] + bias[R + 2], k1 = v4[3] + bias[R + 3];
          int hc = R >> 1;
          out0[((size_t)f * 96 + hc) * PIX + pc]     = f2h(q0 * k0 * SCALE_QK);
          out0[((size_t)f * 96 + hc + 1) * PIX + pc] = f2h(q1 * k1 * SCALE_QK);
        } else {
          for (int r = 0; r < 4; ++r) {
            int vr = R + r - 192;
            if (vr < 96) out1[((size_t)f * 96 + vr) * PIX + pc] = f2b(v4[r] + bias[R + r]);
          }
        }
      } else if (MODE == 1) {
        for (int r = 0; r < 4; ++r) {
          int o = R + r;
          if (o < 294) out0[((size_t)fc * 294 + o) * PIX + pc] = f2b(v4[r] + bias[o]);
        }
      } else {
        int b = f >> 3, d = f & 7;
        for (int r = 0; r < 4; ++r) {
          int o = R + r;
          if (o < 96) {
            size_t gi = ((size_t)(b * 96 + o) * 8 + d) * PIX + pc;
            outF[gi] = resid[gi] + v4[r] + bias[o];
          }
        }
      }
    }
}

// ---------------- grouped 7x7 conv + GELU (v_pk_fma_f16, sliding window) -----
// h: (f, 96, 9216) f16 -> a_t BLOCKED-4: a_t[((f*24+g)*PIX + pix)*4 + co].
// block = (group g of 4 ch, 16-row tile, frame). thread = (y of 16, xseg of 6).
// LDS image: 4ch x 22 rows x 104 cols u16, col = ax+4 (left pad 4, dword aligned).
// Packed f16 acc pairs (out[2p],out[2p+1]); odd taps via v_alignbit shifted copies;
// weights duplicated (w,w) in WCV, consumed from SGPRs via pkfma_s (VOP3P 1-SGPR
// rule). History: builtin f16x2 fma scalarized (~70us); asm all-"v" regressed
// to 97us (weight mov flood); this form targets true 2 MAC/slot.
__global__ __launch_bounds__(256, 4) void k_conv(const u16* __restrict__ h,
                                                 const unsigned int* __restrict__ wcv,
                                                 const float* __restrict__ b_a1,
                                                 u16* __restrict__ a_t) {
  __shared__ u16 li[4 * 22 * 104];   // 18.3KB
  const int g = blockIdx.x, ty = blockIdx.y, f = blockIdx.z;
  const int tid = threadIdx.x;
  const int gb = g * 4, y0 = ty * 16;
  // dword staging: 4ch x 22 rows x 52 dwords; dword jd covers ax = 2jd-4, 2jd-3.
  for (int idx = tid; idx < 4576; idx += 256) {
    int row = idx / 52;            // ch*22 + rr
    int jd  = idx - row * 52;
    int ch  = row / 22;
    int rr  = row - ch * 22;
    int ay  = y0 - 3 + rr;
    unsigned int val = 0;
    if (jd >= 2 && jd <= 49 && ay >= 0 && ay < 96)
      val = *(const unsigned int*)&h[((size_t)f * 96 + gb + ch) * PIX + ay * 96 + (2 * jd - 4)];
    *(unsigned int*)&li[row * 104 + 2 * jd] = val;
  }
  __syncthreads();

  const int y = tid >> 4;            // 0..15
  const int x0 = (tid & 15) * 6;     // 0..90 (even)
  unsigned int pacc[4][3];
  #pragma unroll
  for (int co = 0; co < 4; ++co)
    #pragma unroll
    for (int p = 0; p < 3; ++p) pacc[co][p] = 0u;

  for (int ch = 0; ch < 4; ++ch) {
    const unsigned int* wch = &wcv[784 * g + 196 * ch];
    for (int ky = 0; ky < 7; ++ky) {
      const unsigned int* lsrc =
          (const unsigned int*)&li[(ch * 22 + (y + ky)) * 104 + x0];
      unsigned int D0 = lsrc[0], D1 = lsrc[1], D2 = lsrc[2], D3 = lsrc[3];
      unsigned int D4 = lsrc[4], D5 = lsrc[5], D6 = lsrc[6];
      unsigned int S0 = __builtin_amdgcn_alignbit(D1, D0, 16);
      unsigned int S1 = __builtin_amdgcn_alignbit(D2, D1, 16);
      unsigned int S2 = __builtin_amdgcn_alignbit(D3, D2, 16);
      unsigned int S3 = __builtin_amdgcn_alignbit(D4, D3, 16);
      unsigned int S4 = __builtin_amdgcn_alignbit(D5, D4, 16);
      unsigned int S5 = __builtin_amdgcn_alignbit(D6, D5, 16);
      const unsigned int* wb = wch + 28 * ky;
      #pragma unroll
      for (int co = 0; co < 4; ++co) {
        unsigned int w0 = wb[co * 7 + 0], w1 = wb[co * 7 + 1];
        unsigned int w2 = wb[co * 7 + 2], w3 = wb[co * 7 + 3];
        unsigned int w4 = wb[co * 7 + 4], w5 = wb[co * 7 + 5];
        unsigned int w6 = wb[co * 7 + 6];
        unsigned int a;
        // pair p: tap kx reads cols (x0+2p+1+kx, x0+2p+2+kx): odd s -> S, even s -> D
        a = pacc[co][0];
        a = pkfma_s(w0, S0, a); a = pkfma_s(w1, D1, a); a = pkfma_s(w2, S1, a);
        a = pkfma_s(w3, D2, a); a = pkfma_s(w4, S2, a); a = pkfma_s(w5, D3, a);
        a = pkfma_s(w6, S3, a); pacc[co][0] = a;
        a = pacc[co][1];
        a = pkfma_s(w0, S1, a); a = pkfma_s(w1, D2, a); a = pkfma_s(w2, S2, a);
        a = pkfma_s(w3, D3, a); a = pkfma_s(w4, S3, a); a = pkfma_s(w5, D4, a);
        a = pkfma_s(w6, S4, a); pacc[co][1] = a;
        a = pacc[co][2];
        a = pkfma_s(w0, S2, a); a = pkfma_s(w1, D3, a); a = pkfma_s(w2, S3, a);
        a = pkfma_s(w3, D4, a); a = pkfma_s(w4, S4, a); a = pkfma_s(w5, D5, a);
        a = pkfma_s(w6, S5, a); pacc[co][2] = a;
      }
    }
  }

  // blocked-4 store: 48B contiguous per thread, full-line coalesced per wave.
  size_t obase = ((size_t)(f * 24 + g) * PIX + (size_t)(y0 + y) * 96 + x0) * 4;
  float bv0 = b_a1[gb + 0], bv1 = b_a1[gb + 1], bv2 = b_a1[gb + 2], bv3 = b_a1[gb + 3];
  #pragma unroll
  for (int p = 0; p < 3; ++p) {
    ushort8 r8;
    #pragma unroll
    for (int co = 0; co < 4; ++co) {
      float bv = (co == 0) ? bv0 : (co == 1) ? bv1 : (co == 2) ? bv2 : bv3;
      f16x2 v = upk(pacc[co][p]);
      float a0 = (float)v[0] + bv, a1 = (float)v[1] + bv;
      r8[co]     = f2b(0.5f * a0 * (1.f + erff(a0 * 0.70710678118f)));
      r8[co + 4] = f2b(0.5f * a1 * (1.f + erff(a1 * 0.70710678118f)));
    }
    *(ushort8*)&a_t[obase + p * 8] = r8;
  }
}

// ---------------- 49-tap window aggregation (8-frame chunk) ----------------
// attn_c: (8, 294, 9216) bf16, v: (f, 96, 9216) bf16 -> out_t BLOCKED-4:
// out_t[((f*24+cq)*PIX + pix)*4 + ch].
// XCD swizzle: the 4 cquads sharing one head's 49 attn planes get the same
// wgid%8 (same XCD under round-robin dispatch) and adjacent dispatch slots,
// so attn_c re-reads hit that XCD's L2 instead of HBM.
// Bijection: 1152 = 8 xcd * 4 member * 36 slot.
__global__ __launch_bounds__(256, 4) void k_aggr(const u16* __restrict__ attn_c,
                                                 const u16* __restrict__ v,
                                                 u16* __restrict__ out_t,
                                                 int fbase) {
  __shared__ u16 lv[4 * 22 * 104];   // 18.3KB
  const int wgid = blockIdx.x + 24 * (blockIdx.y + 6 * blockIdx.z);
  const int xcd = wgid & 7;
  const int member = (wgid >> 3) & 3;
  const int slot = wgid >> 5;
  const int gidx = slot * 8 + xcd;       // 0..287
  const int cqh = gidx % 6;
  const int ty = (gidx / 6) % 6;
  const int fc = gidx / 36;
  const int cq = cqh * 4 + member;
  const int f = fbase + fc;
  const int tid = threadIdx.x;
  const int c0 = cq * 4, y0 = ty * 16;
  const int head = c0 >> 4;
  for (int idx = tid; idx < 4 * 22 * 104; idx += 256) {
    int col = idx % 104;
    int rr = (idx / 104) % 22;
    int ch = idx / (104 * 22);
    int ax = col - 3, ay = y0 - 3 + rr;
    u16 val = 0;
    if (ax >= 0 && ax < 96 && ay >= 0 && ay < 96)
      val = v[((size_t)f * 96 + c0 + ch) * PIX + ay * 96 + ax];
    lv[idx] = val;
  }
  __syncthreads();

  const int y = tid >> 4;            // 0..15
  const int x0 = (tid & 15) * 6;     // 0..90
  float acc[4][6] = {};
  const int prow = (y0 + y) * 96 + x0;

  for (int i = 0; i < 7; ++i) {
    float vrow[4][12];
    #pragma unroll
    for (int ch = 0; ch < 4; ++ch) {
      const unsigned int* lsrc = (const unsigned int*)&lv[(ch * 22 + (y + i)) * 104 + x0];
      #pragma unroll
      for (int t = 0; t < 6; ++t) {
        unsigned int u = lsrc[t];
        vrow[ch][2 * t]     = lo2f(u);
        vrow[ch][2 * t + 1] = hi2f(u);
      }
    }
    #pragma unroll
    for (int j = 0; j < 7; ++j) {
      const unsigned int* asrc = (const unsigned int*)
          &attn_c[((size_t)fc * 294 + head * 49 + i * 7 + j) * PIX + prow];
      unsigned int u0 = asrc[0], u1 = asrc[1], u2 = asrc[2];
      float av[6] = {lo2f(u0), hi2f(u0), lo2f(u1), hi2f(u1), lo2f(u2), hi2f(u2)};
      #pragma unroll
      for (int o = 0; o < 6; ++o)
        #pragma unroll
        for (int ch = 0; ch < 4; ++ch)
          acc[ch][o] += av[o] * vrow[ch][o + j];
    }
  }

  // blocked-4 store: 48B contiguous per thread.
  size_t obase = ((size_t)(f * 24 + cq) * PIX + prow) * 4;
  #pragma unroll
  for (int o = 0; o < 6; o += 2) {
    ushort8 r8;
    #pragma unroll
    for (int ch = 0; ch < 4; ++ch) {
      r8[ch]     = f2b(acc[ch][o]);
      r8[ch + 4] = f2b(acc[ch][o + 1]);
    }
    *(ushort8*)&out_t[obase + o * 4] = r8;
  }
}

extern "C" void kernel_launch(void* const* d_in, const int* in_sizes, int n_in,
                              void* d_out, int out_size, void* d_ws, size_t ws_size,
                              hipStream_t stream) {
  const float* x    = (const float*)d_in[0];
  const float* ln_g = (const float*)d_in[1];
  const float* ln_b = (const float*)d_in[2];
  const float* w_qk = (const float*)d_in[3];
  const float* b_qk = (const float*)d_in[4];
  const float* w_v  = (const float*)d_in[5];
  const float* b_v  = (const float*)d_in[6];
  const float* w_a1 = (const float*)d_in[7];
  const float* b_a1 = (const float*)d_in[8];
  const float* w_a2 = (const float*)d_in[9];
  const float* b_a2 = (const float*)d_in[10];
  const float* g_mul= (const float*)d_in[11];
  const float* g_add= (const float*)d_in[12];
  const float* w_p  = (const float*)d_in[13];
  const float* b_p  = (const float*)d_in[14];

  char* ws = (char*)d_ws;
  u16*   W2    = (u16*)(ws + 0);
  float* bias2 = (float*)(ws + 61440);
  u16*   WA2   = (u16*)(ws + 62720);
  float* biasA2= (float*)(ws + 124160);
  u16*   WP    = (u16*)(ws + 125440);
  float* biasP = (float*)(ws + 150016);
  unsigned int* WCV = (unsigned int*)(ws + 150528);
  u16*   xn_t  = (u16*)(ws + 225792);       // reused as a_t
  u16*   hbuf  = (u16*)(ws + 28537344);     // reused as out_t
  u16*   vbuf  = (u16*)(ws + 56848896);
  u16*   attnc = (u16*)(ws + 85160448);     // 8-frame attn chunk (8 x 294 x 9216)

  k_prep<<<365, 256, 0, stream>>>(w_qk, b_qk, w_v, b_v, w_a1, w_a2, b_a2, g_mul, g_add,
                                  w_p, b_p, W2, bias2, WA2, biasA2, WP, biasP, WCV);
  k_ln<<<576, 256, 0, stream>>>(x, ln_g, ln_b, xn_t);
  k_gemm<0><<<dim3(144, 5, 16), 256, 0, stream>>>(xn_t, W2, bias2, hbuf, vbuf,
                                                  nullptr, nullptr, 0);
  k_conv<<<dim3(24, 6, 16), 256, 0, stream>>>(hbuf, WCV, b_a1, xn_t /*a_t*/);
  for (int c = 0; c < 2; ++c) {
    k_gemm<1><<<dim3(144, 5, 8), 256, 0, stream>>>(xn_t /*a_t*/, WA2, biasA2,
                                                   attnc, nullptr, nullptr, nullptr, c * 8);
    k_aggr<<<dim3(24, 6, 8), 256, 0, stream>>>(attnc, vbuf, hbuf /*out_t*/, c * 8);
  }
  k_gemm<2><<<dim3(144, 2, 16), 256, 0, stream>>>(hbuf /*out_t*/, WP, biasP,
                                                  nullptr, nullptr, (float*)d_out, x, 0);
}

// Round 9
// 378.686 us; speedup vs baseline: 1.0490x; 1.0490x over previous
//
#include <hip/hip_runtime.h>
#include <hip/hip_bf16.h>

// ELSA block. Inputs: float32. Output: float32. Internal: bf16 (MFMA) + f16 (conv).
// Pipeline:
//  k_prep: weight repack (interleave q/k rows, pad, fold ghost, dup conv w as f16 (w,w))
//  k_gemm<0>: FUSED LayerNorm (in-block, 4-lane shfl reduce) + qkv projection.
//             One block per (64-pix, frame); loops all 5 cot W-slices against the
//             staged X tile -> h=(q*k*scale) f16, v bf16.
//  k_conv: grouped 7x7 conv + exact GELU (packed f16 fma builtin, R6 form) -> a_t BLOCKED-4
//  2 chunks of 8 frames:  k_gemm<1>: 294-ch logits + ghost -> attn_c (8f,294,p)
//                         k_aggr: 49-tap window aggregation -> out_t BLOCKED-4
//                                 (XCD-swizzled: 4 cquads of a head co-resident)
//  k_gemm<2>: out proj + bias + f32 residual -> d_out f32 (B,C,D,H,W)
// Workspace (bytes), total 128,512,512 (~122.6 MB):
//  [0)        W2 (320x96 bf16)  61,440
//  [61440)    bias2 (320 f32)    1,280
//  [62720)    WA2 (320x96 bf16) 61,440
//  [124160)   biasA2 (320 f32)   1,280
//  [125440)   WP (128x96 bf16)  24,576
//  [150016)   biasP (128 f32)      512
//  [150528)   WCV (24x4x7x4x7 uint dup-f16) 75,264
//  [225792)   a_t          28,311,552
//  [28537344) h / out_t    28,311,552
//  [56848896) v            28,311,552
//  [85160448) attn_c (8x294x9216 bf16) 43,352,064

typedef unsigned short u16;
typedef short bf16x8 __attribute__((ext_vector_type(8)));
typedef float floatx4 __attribute__((ext_vector_type(4)));
typedef unsigned short ushort8 __attribute__((ext_vector_type(8)));
typedef unsigned int uint4v __attribute__((ext_vector_type(4)));
typedef unsigned int uint2v __attribute__((ext_vector_type(2)));
typedef _Float16 f16x2 __attribute__((ext_vector_type(2)));

#define PIX      9216
#define SCALE_QK 0.25f

__device__ __forceinline__ float lo2f(unsigned int u) {
  union { unsigned int i; float f; } z; z.i = u << 16; return z.f;
}
__device__ __forceinline__ float hi2f(unsigned int u) {
  union { unsigned int i; float f; } z; z.i = u & 0xFFFF0000u; return z.f;
}
__device__ __forceinline__ u16 f2b(float f) {
  union { float f; unsigned int i; } z; z.f = f;
  unsigned int r = z.i + 0x7fffu + ((z.i >> 16) & 1u);
  return (u16)(r >> 16);
}
__device__ __forceinline__ u16 f2h(float f) {
  _Float16 h = (_Float16)f;
  union { _Float16 h; u16 u; } z; z.h = h; return z.u;
}
__device__ __forceinline__ f16x2 upk(unsigned int u) {
  union { unsigned int u; f16x2 h; } z; z.u = u; return z.h;
}
__device__ __forceinline__ f16x2 pkfma(unsigned int w, unsigned int x, f16x2 c) {
#if __has_builtin(__builtin_elementwise_fma)
  return __builtin_elementwise_fma(upk(w), upk(x), c);
#else
  return upk(w) * upk(x) + c;
#endif
}

// ---------------- weight prep (f32 in, bf16/f16/f32 out) ----------------
__global__ void k_prep(const float* __restrict__ w_qk, const float* __restrict__ b_qk,
                       const float* __restrict__ w_v,  const float* __restrict__ b_v,
                       const float* __restrict__ w_a1,
                       const float* __restrict__ w_a2, const float* __restrict__ b_a2,
                       const float* __restrict__ g_mul,const float* __restrict__ g_add,
                       const float* __restrict__ w_p,  const float* __restrict__ b_p,
                       u16* __restrict__ W2, float* __restrict__ bias2,
                       u16* __restrict__ WA2, float* __restrict__ biasA2,
                       u16* __restrict__ WP, float* __restrict__ biasP,
                       unsigned int* __restrict__ WCV) {
  int i = blockIdx.x * 256 + threadIdx.x;
  if (i < 30720) {                       // W2: 320*96
    int r = i / 96, ci = i % 96;
    float val = 0.f;
    if (r < 192) { int src = (r & 1) ? (96 + (r >> 1)) : (r >> 1); val = w_qk[src * 96 + ci]; }
    else if (r < 288) val = w_v[(r - 192) * 96 + ci];
    W2[i] = f2b(val);
  } else if (i < 31040) {                // bias2: 320
    int r = i - 30720; float bv = 0.f;
    if (r < 192) { int src = (r & 1) ? (96 + (r >> 1)) : (r >> 1); bv = b_qk[src]; }
    else if (r < 288) bv = b_v[r - 192];
    bias2[r] = bv;
  } else if (i < 61760) {                // WA2: 320*96
    int j = i - 31040; int r = j / 96, ci = j % 96;
    float wv = 0.f;
    if (r < 294) wv = w_a2[r * 96 + ci] * g_mul[r];
    WA2[j] = f2b(wv);
  } else if (i < 62080) {                // biasA2: 320
    int r = i - 61760; float bv = 0.f;
    if (r < 294) bv = b_a2[r] * g_mul[r] + g_add[r];
    biasA2[r] = bv;
  } else if (i < 74368) {                // WP: 128*96
    int j = i - 62080; int r = j / 96;
    WP[j] = (r < 96) ? f2b(w_p[j]) : (u16)0;
  } else if (i < 74496) {                // biasP: 128
    int r = i - 74368;
    biasP[r] = (r < 96) ? b_p[r] : 0.f;
  } else if (i < 93312) {                // WCV: dup f16 [g][ch][ky][co][kx], 18816 uints
    int j = i - 74496;
    int kx = j % 7, co = (j / 7) & 3, ky = (j / 28) % 7, ch = (j / 196) & 3, g = j / 784;
    float w = w_a1[(g * 4 + co) * 196 + ch * 49 + ky * 7 + kx];
    unsigned int hw = f2h(w);
    WCV[j] = hw | (hw << 16);
  }
}

// ---------------- MFMA GEMM (64p x all-cout, K=96, cot loop in-block) --------
// One block per (64-pixel strip, frame); loops cot = 0..NC-1 over W slices.
// MODE 0: fused LayerNorm staging from x f32 (xf=resid param), lg/lb; writes
//         h f16 (out0) + v bf16 (out1). Grid (144,16). X param unused.
// MODE 1: X = a_t BLOCKED-4 gather; attn chunk -> out0, frame-local blockIdx.y,
//         f = fArg + blockIdx.y. Grid (144,8).
// MODE 2: X = out_t BLOCKED-4; final f32 out (outF=d_out) + resid. Grid (144,16).
template <int MODE>
__global__ __launch_bounds__(256) void k_gemm(const u16* __restrict__ X,
                                              const u16* __restrict__ W,
                                              const float* __restrict__ bias,
                                              u16* __restrict__ out0,
                                              u16* __restrict__ out1,
                                              float* __restrict__ outF,
                                              const float* __restrict__ resid,
                                              const float* __restrict__ lg,
                                              const float* __restrict__ lb,
                                              int fArg) {
  constexpr int NC = (MODE == 2) ? 2 : 5;
  __shared__ u16 lw[64 * 104];
  __shared__ u16 lx[64 * 104];
  const int tid = threadIdx.x;
  const int fc = blockIdx.y;
  const int f = (MODE == 1) ? (fArg + fc) : fc;
  const int p0 = blockIdx.x * 64;

  if constexpr (MODE == 0) {
    // Fused LayerNorm: thread (pix = tid>>2, sub = tid&3) loads 24 channels of
    // its pixel from x f32 (lanes 4-aligned per pixel -> 64B coalesced segments),
    // reduces mean/var via 4-lane shfl_xor, writes normalized bf16 into lx.
    const int pix = tid >> 2, sub = tid & 3;
    const int b = f >> 3, d = f & 7;
    const size_t xbase = ((size_t)(b * 768 + d)) * PIX + p0 + pix;
    float xv[24];
    #pragma unroll
    for (int k = 0; k < 24; ++k)
      xv[k] = resid[xbase + (size_t)(sub * 24 + k) * 73728];
    float s = 0.f, ss = 0.f;
    #pragma unroll
    for (int k = 0; k < 24; ++k) { s += xv[k]; ss += xv[k] * xv[k]; }
    s += __shfl_xor(s, 1);  ss += __shfl_xor(ss, 1);
    s += __shfl_xor(s, 2);  ss += __shfl_xor(ss, 2);
    float mu = s * (1.f / 96.f);
    float var = ss * (1.f / 96.f) - mu * mu;
    float rs = rsqrtf(var + 1e-5f);
    unsigned int* dst = (unsigned int*)&lx[pix * 104 + sub * 24];
    #pragma unroll
    for (int k = 0; k < 12; ++k) {
      int c = sub * 24 + 2 * k;
      u16 lo = f2b((xv[2 * k]     - mu) * rs * lg[c]     + lb[c]);
      u16 hi = f2b((xv[2 * k + 1] - mu) * rs * lg[c + 1] + lb[c + 1]);
      dst[k] = (unsigned int)lo | ((unsigned int)hi << 16);
    }
  } else {
    // X is blocked-4: X[((f*24 + g)*PIX + p)*4 + co]. Channel-oct s2 spans
    // groups 2*s2, 2*s2+1. r fastest across lanes -> contiguous 8B reads.
    for (int idx = tid; idx < 768; idx += 256) {
      int s2 = idx >> 6, r = idx & 63;
      const u16* src0 = &X[((size_t)(f * 24 + 2 * s2) * PIX + p0 + r) * 4];
      const u16* src1 = &X[((size_t)(f * 24 + 2 * s2 + 1) * PIX + p0 + r) * 4];
      *(uint2v*)&lx[r * 104 + s2 * 8]     = *(const uint2v*)src0;
      *(uint2v*)&lx[r * 104 + s2 * 8 + 4] = *(const uint2v*)src1;
    }
  }
  __syncthreads();

  const int lane = tid & 63, wv = tid >> 6;
  const int cw = (wv >> 1) * 32, pw = (wv & 1) * 32;
  const int m = lane & 15, quad = lane >> 4;

  for (int cot = 0; cot < NC; ++cot) {
    for (int ch = tid; ch < 768; ch += 256) {
      int r = ch / 12, s2 = ch % 12;
      *(uint4v*)&lw[r * 104 + s2 * 8] =
          *(const uint4v*)&W[(size_t)(cot * 64 + r) * 96 + s2 * 8];
    }
    __syncthreads();

    floatx4 acc[2][2] = {};
    for (int ks = 0; ks < 3; ++ks) {
      int ko = ks * 32 + quad * 8;
      bf16x8 a0 = *(const bf16x8*)&lw[(cw + m) * 104 + ko];
      bf16x8 a1 = *(const bf16x8*)&lw[(cw + 16 + m) * 104 + ko];
      bf16x8 b0 = *(const bf16x8*)&lx[(pw + m) * 104 + ko];
      bf16x8 b1 = *(const bf16x8*)&lx[(pw + 16 + m) * 104 + ko];
      acc[0][0] = __builtin_amdgcn_mfma_f32_16x16x32_bf16(a0, b0, acc[0][0], 0, 0, 0);
      acc[0][1] = __builtin_amdgcn_mfma_f32_16x16x32_bf16(a0, b1, acc[0][1], 0, 0, 0);
      acc[1][0] = __builtin_amdgcn_mfma_f32_16x16x32_bf16(a1, b0, acc[1][0], 0, 0, 0);
      acc[1][1] = __builtin_amdgcn_mfma_f32_16x16x32_bf16(a1, b1, acc[1][1], 0, 0, 0);
    }

    for (int mt = 0; mt < 2; ++mt)
      for (int nt = 0; nt < 2; ++nt) {
        int R = cot * 64 + cw + mt * 16 + quad * 4;
        int pc = p0 + pw + nt * 16 + m;
        floatx4 v4 = acc[mt][nt];
        if (MODE == 0) {
          if (cot < 3) {
            float q0 = v4[0] + bias[R + 0], k0 = v4[1] + bias[R + 1];
            float q1 = v4[2] + bias[R + 2], k1 = v4[3] + bias[R + 3];
            int hc = R >> 1;
            out0[((size_t)f * 96 + hc) * PIX + pc]     = f2h(q0 * k0 * SCALE_QK);
            out0[((size_t)f * 96 + hc + 1) * PIX + pc] = f2h(q1 * k1 * SCALE_QK);
          } else {
            for (int r = 0; r < 4; ++r) {
              int vr = R + r - 192;
              if (vr < 96) out1[((size_t)f * 96 + vr) * PIX + pc] = f2b(v4[r] + bias[R + r]);
            }
          }
        } else if (MODE == 1) {
          for (int r = 0; r < 4; ++r) {
            int o = R + r;
            if (o < 294) out0[((size_t)fc * 294 + o) * PIX + pc] = f2b(v4[r] + bias[o]);
          }
        } else {
          int b = f >> 3, dd = f & 7;
          for (int r = 0; r < 4; ++r) {
            int o = R + r;
            if (o < 96) {
              size_t gi = ((size_t)(b * 96 + o) * 8 + dd) * PIX + pc;
              outF[gi] = resid[gi] + v4[r] + bias[o];
            }
          }
        }
      }
    __syncthreads();
  }
}

// ---------------- grouped 7x7 conv + GELU (packed f16 fma, sliding window) ---
// h: (f, 96, 9216) f16 -> a_t BLOCKED-4: a_t[((f*24+g)*PIX + pix)*4 + co].
// block = (group g of 4 ch, 16-row tile, frame). thread = (y of 16, xseg of 6).
// LDS image: 4ch x 22 rows x 104 cols u16, col = ax+4 (left pad 4, dword aligned).
// Best-measured form (R6, 70.7us). Encoding variants all >= this: fma_mix 74,
// asm all-"v" 97 (weight mov flood), asm "s"-weight 74.5 (SGPR reload stalls).
__global__ __launch_bounds__(256, 4) void k_conv(const u16* __restrict__ h,
                                                 const unsigned int* __restrict__ wcv,
                                                 const float* __restrict__ b_a1,
                                                 u16* __restrict__ a_t) {
  __shared__ u16 li[4 * 22 * 104];   // 18.3KB
  const int g = blockIdx.x, ty = blockIdx.y, f = blockIdx.z;
  const int tid = threadIdx.x;
  const int gb = g * 4, y0 = ty * 16;
  // dword staging: 4ch x 22 rows x 52 dwords; dword jd covers ax = 2jd-4, 2jd-3.
  for (int idx = tid; idx < 4576; idx += 256) {
    int row = idx / 52;            // ch*22 + rr
    int jd  = idx - row * 52;
    int ch  = row / 22;
    int rr  = row - ch * 22;
    int ay  = y0 - 3 + rr;
    unsigned int val = 0;
    if (jd >= 2 && jd <= 49 && ay >= 0 && ay < 96)
      val = *(const unsigned int*)&h[((size_t)f * 96 + gb + ch) * PIX + ay * 96 + (2 * jd - 4)];
    *(unsigned int*)&li[row * 104 + 2 * jd] = val;
  }
  __syncthreads();

  const int y = tid >> 4;            // 0..15
  const int x0 = (tid & 15) * 6;     // 0..90 (even)
  f16x2 pacc[4][3];
  #pragma unroll
  for (int co = 0; co < 4; ++co)
    #pragma unroll
    for (int p = 0; p < 3; ++p) pacc[co][p] = upk(0u);

  for (int ch = 0; ch < 4; ++ch) {
    const unsigned int* wch = &wcv[784 * g + 196 * ch];
    for (int ky = 0; ky < 7; ++ky) {
      const unsigned int* lsrc =
          (const unsigned int*)&li[(ch * 22 + (y + ky)) * 104 + x0];
      unsigned int D0 = lsrc[0], D1 = lsrc[1], D2 = lsrc[2], D3 = lsrc[3];
      unsigned int D4 = lsrc[4], D5 = lsrc[5], D6 = lsrc[6];
      unsigned int S0 = __builtin_amdgcn_alignbit(D1, D0, 16);
      unsigned int S1 = __builtin_amdgcn_alignbit(D2, D1, 16);
      unsigned int S2 = __builtin_amdgcn_alignbit(D3, D2, 16);
      unsigned int S3 = __builtin_amdgcn_alignbit(D4, D3, 16);
      unsigned int S4 = __builtin_amdgcn_alignbit(D5, D4, 16);
      unsigned int S5 = __builtin_amdgcn_alignbit(D6, D5, 16);
      const unsigned int* wb = wch + 28 * ky;
      #pragma unroll
      for (int co = 0; co < 4; ++co) {
        unsigned int w0 = wb[co * 7 + 0], w1 = wb[co * 7 + 1];
        unsigned int w2 = wb[co * 7 + 2], w3 = wb[co * 7 + 3];
        unsigned int w4 = wb[co * 7 + 4], w5 = wb[co * 7 + 5];
        unsigned int w6 = wb[co * 7 + 6];
        f16x2 a;
        // pair p: tap kx reads cols (x0+2p+1+kx, x0+2p+2+kx): odd s -> S, even s -> D
        a = pacc[co][0];
        a = pkfma(w0, S0, a); a = pkfma(w1, D1, a); a = pkfma(w2, S1, a);
        a = pkfma(w3, D2, a); a = pkfma(w4, S2, a); a = pkfma(w5, D3, a);
        a = pkfma(w6, S3, a); pacc[co][0] = a;
        a = pacc[co][1];
        a = pkfma(w0, S1, a); a = pkfma(w1, D2, a); a = pkfma(w2, S2, a);
        a = pkfma(w3, D3, a); a = pkfma(w4, S3, a); a = pkfma(w5, D4, a);
        a = pkfma(w6, S4, a); pacc[co][1] = a;
        a = pacc[co][2];
        a = pkfma(w0, S2, a); a = pkfma(w1, D3, a); a = pkfma(w2, S3, a);
        a = pkfma(w3, D4, a); a = pkfma(w4, S4, a); a = pkfma(w5, D5, a);
        a = pkfma(w6, S5, a); pacc[co][2] = a;
      }
    }
  }

  // blocked-4 store: 48B contiguous per thread, full-line coalesced per wave.
  size_t obase = ((size_t)(f * 24 + g) * PIX + (size_t)(y0 + y) * 96 + x0) * 4;
  float bv0 = b_a1[gb + 0], bv1 = b_a1[gb + 1], bv2 = b_a1[gb + 2], bv3 = b_a1[gb + 3];
  #pragma unroll
  for (int p = 0; p < 3; ++p) {
    ushort8 r8;
    #pragma unroll
    for (int co = 0; co < 4; ++co) {
      float bv = (co == 0) ? bv0 : (co == 1) ? bv1 : (co == 2) ? bv2 : bv3;
      f16x2 v = pacc[co][p];
      float a0 = (float)v[0] + bv, a1 = (float)v[1] + bv;
      r8[co]     = f2b(0.5f * a0 * (1.f + erff(a0 * 0.70710678118f)));
      r8[co + 4] = f2b(0.5f * a1 * (1.f + erff(a1 * 0.70710678118f)));
    }
    *(ushort8*)&a_t[obase + p * 8] = r8;
  }
}

// ---------------- 49-tap window aggregation (8-frame chunk) ----------------
// attn_c: (8, 294, 9216) bf16, v: (f, 96, 9216) bf16 -> out_t BLOCKED-4:
// out_t[((f*24+cq)*PIX + pix)*4 + ch].
// XCD swizzle: the 4 cquads sharing one head's 49 attn planes get the same
// wgid%8 (same XCD under round-robin dispatch) and adjacent dispatch slots,
// so attn_c re-reads hit that XCD's L2 instead of HBM.
// Bijection: 1152 = 8 xcd * 4 member * 36 slot.
__global__ __launch_bounds__(256, 4) void k_aggr(const u16* __restrict__ attn_c,
                                                 const u16* __restrict__ v,
                                                 u16* __restrict__ out_t,
                                                 int fbase) {
  __shared__ u16 lv[4 * 22 * 104];   // 18.3KB
  const int wgid = blockIdx.x + 24 * (blockIdx.y + 6 * blockIdx.z);
  const int xcd = wgid & 7;
  const int member = (wgid >> 3) & 3;
  const int slot = wgid >> 5;
  const int gidx = slot * 8 + xcd;       // 0..287
  const int cqh = gidx % 6;
  const int ty = (gidx / 6) % 6;
  const int fc = gidx / 36;
  const int cq = cqh * 4 + member;
  const int f = fbase + fc;
  const int tid = threadIdx.x;
  const int c0 = cq * 4, y0 = ty * 16;
  const int head = c0 >> 4;
  for (int idx = tid; idx < 4 * 22 * 104; idx += 256) {
    int col = idx % 104;
    int rr = (idx / 104) % 22;
    int ch = idx / (104 * 22);
    int ax = col - 3, ay = y0 - 3 + rr;
    u16 val = 0;
    if (ax >= 0 && ax < 96 && ay >= 0 && ay < 96)
      val = v[((size_t)f * 96 + c0 + ch) * PIX + ay * 96 + ax];
    lv[idx] = val;
  }
  __syncthreads();

  const int y = tid >> 4;            // 0..15
  const int x0 = (tid & 15) * 6;     // 0..90
  float acc[4][6] = {};
  const int prow = (y0 + y) * 96 + x0;

  for (int i = 0; i < 7; ++i) {
    float vrow[4][12];
    #pragma unroll
    for (int ch = 0; ch < 4; ++ch) {
      const unsigned int* lsrc = (const unsigned int*)&lv[(ch * 22 + (y + i)) * 104 + x0];
      #pragma unroll
      for (int t = 0; t < 6; ++t) {
        unsigned int u = lsrc[t];
        vrow[ch][2 * t]     = lo2f(u);
        vrow[ch][2 * t + 1] = hi2f(u);
      }
    }
    #pragma unroll
    for (int j = 0; j < 7; ++j) {
      const unsigned int* asrc = (const unsigned int*)
          &attn_c[((size_t)fc * 294 + head * 49 + i * 7 + j) * PIX + prow];
      unsigned int u0 = asrc[0], u1 = asrc[1], u2 = asrc[2];
      float av[6] = {lo2f(u0), hi2f(u0), lo2f(u1), hi2f(u1), lo2f(u2), hi2f(u2)};
      #pragma unroll
      for (int o = 0; o < 6; ++o)
        #pragma unroll
        for (int ch = 0; ch < 4; ++ch)
          acc[ch][o] += av[o] * vrow[ch][o + j];
    }
  }

  // blocked-4 store: 48B contiguous per thread.
  size_t obase = ((size_t)(f * 24 + cq) * PIX + prow) * 4;
  #pragma unroll
  for (int o = 0; o < 6; o += 2) {
    ushort8 r8;
    #pragma unroll
    for (int ch = 0; ch < 4; ++ch) {
      r8[ch]     = f2b(acc[ch][o]);
      r8[ch + 4] = f2b(acc[ch][o + 1]);
    }
    *(ushort8*)&out_t[obase + o * 4] = r8;
  }
}

extern "C" void kernel_launch(void* const* d_in, const int* in_sizes, int n_in,
                              void* d_out, int out_size, void* d_ws, size_t ws_size,
                              hipStream_t stream) {
  const float* x    = (const float*)d_in[0];
  const float* ln_g = (const float*)d_in[1];
  const float* ln_b = (const float*)d_in[2];
  const float* w_qk = (const float*)d_in[3];
  const float* b_qk = (const float*)d_in[4];
  const float* w_v  = (const float*)d_in[5];
  const float* b_v  = (const float*)d_in[6];
  const float* w_a1 = (const float*)d_in[7];
  const float* b_a1 = (const float*)d_in[8];
  const float* w_a2 = (const float*)d_in[9];
  const float* b_a2 = (const float*)d_in[10];
  const float* g_mul= (const float*)d_in[11];
  const float* g_add= (const float*)d_in[12];
  const float* w_p  = (const float*)d_in[13];
  const float* b_p  = (const float*)d_in[14];

  char* ws = (char*)d_ws;
  u16*   W2    = (u16*)(ws + 0);
  float* bias2 = (float*)(ws + 61440);
  u16*   WA2   = (u16*)(ws + 62720);
  float* biasA2= (float*)(ws + 124160);
  u16*   WP    = (u16*)(ws + 125440);
  float* biasP = (float*)(ws + 150016);
  unsigned int* WCV = (unsigned int*)(ws + 150528);
  u16*   a_t   = (u16*)(ws + 225792);
  u16*   hbuf  = (u16*)(ws + 28537344);     // reused as out_t
  u16*   vbuf  = (u16*)(ws + 56848896);
  u16*   attnc = (u16*)(ws + 85160448);     // 8-frame attn chunk (8 x 294 x 9216)

  k_prep<<<365, 256, 0, stream>>>(w_qk, b_qk, w_v, b_v, w_a1, w_a2, b_a2, g_mul, g_add,
                                  w_p, b_p, W2, bias2, WA2, biasA2, WP, biasP, WCV);
  // Fused LN + qkv projection (k_ln eliminated; x read directly, coalesced).
  k_gemm<0><<<dim3(144, 16), 256, 0, stream>>>(nullptr, W2, bias2, hbuf, vbuf,
                                               nullptr, x, ln_g, ln_b, 0);
  k_conv<<<dim3(24, 6, 16), 256, 0, stream>>>(hbuf, WCV, b_a1, a_t);
  for (int c = 0; c < 2; ++c) {
    k_gemm<1><<<dim3(144, 8), 256, 0, stream>>>(a_t, WA2, biasA2,
                                                attnc, nullptr, nullptr, nullptr,
                                                nullptr, nullptr, c * 8);
    k_aggr<<<dim3(24, 6, 8), 256, 0, stream>>>(attnc, vbuf, hbuf /*out_t*/, c * 8);
  }
  k_gemm<2><<<dim3(144, 16), 256, 0, stream>>>(hbuf /*out_t*/, WP, biasP,
                                               nullptr, nullptr, (float*)d_out, x,
                                               nullptr, nullptr, 0);
}

// Round 10
// 356.238 us; speedup vs baseline: 1.1151x; 1.0630x over previous
//
#include <hip/hip_runtime.h>
#include <hip/hip_bf16.h>

// ELSA block. Inputs: float32. Output: float32. Internal: bf16 (MFMA) + f16.
// Pipeline:
//  k_prep: weight repack (interleave q/k rows, pad, fold ghost, dup conv w as f16 (w,w))
//  k_gemm<0>: FUSED LayerNorm + qkv projection -> h f16, v f16 (v consumed only by aggr)
//  k_conv: grouped 7x7 conv + exact GELU (packed f16 fma) -> a_t BLOCKED-4 bf16
//  2 chunks of 8 frames:  k_gemm<1>: 294-ch logits + ghost -> attn_c (8f,294,p) f16
//                         k_aggr: 49-tap window aggregation, PACKED f16 pairs
//                                 (attn dword = operand pair, alignbit v shifts,
//                                 zero unpacks) -> out_t BLOCKED-4 bf16
//  k_gemm<2>: out proj + bias + f32 residual -> d_out f32 (B,C,D,H,W)
// Workspace: same layout as prior rounds (128.5 MB total).

typedef unsigned short u16;
typedef short bf16x8 __attribute__((ext_vector_type(8)));
typedef float floatx4 __attribute__((ext_vector_type(4)));
typedef unsigned short ushort8 __attribute__((ext_vector_type(8)));
typedef unsigned int uint4v __attribute__((ext_vector_type(4)));
typedef unsigned int uint2v __attribute__((ext_vector_type(2)));
typedef _Float16 f16x2 __attribute__((ext_vector_type(2)));

#define PIX      9216
#define SCALE_QK 0.25f

__device__ __forceinline__ float lo2f(unsigned int u) {
  union { unsigned int i; float f; } z; z.i = u << 16; return z.f;
}
__device__ __forceinline__ float hi2f(unsigned int u) {
  union { unsigned int i; float f; } z; z.i = u & 0xFFFF0000u; return z.f;
}
__device__ __forceinline__ u16 f2b(float f) {
  union { float f; unsigned int i; } z; z.f = f;
  unsigned int r = z.i + 0x7fffu + ((z.i >> 16) & 1u);
  return (u16)(r >> 16);
}
__device__ __forceinline__ u16 f2h(float f) {
  _Float16 h = (_Float16)f;
  union { _Float16 h; u16 u; } z; z.h = h; return z.u;
}
__device__ __forceinline__ f16x2 upk(unsigned int u) {
  union { unsigned int u; f16x2 h; } z; z.u = u; return z.h;
}
__device__ __forceinline__ f16x2 pkfma(unsigned int w, unsigned int x, f16x2 c) {
#if __has_builtin(__builtin_elementwise_fma)
  return __builtin_elementwise_fma(upk(w), upk(x), c);
#else
  return upk(w) * upk(x) + c;
#endif
}

// ---------------- weight prep (f32 in, bf16/f16/f32 out) ----------------
__global__ void k_prep(const float* __restrict__ w_qk, const float* __restrict__ b_qk,
                       const float* __restrict__ w_v,  const float* __restrict__ b_v,
                       const float* __restrict__ w_a1,
                       const float* __restrict__ w_a2, const float* __restrict__ b_a2,
                       const float* __restrict__ g_mul,const float* __restrict__ g_add,
                       const float* __restrict__ w_p,  const float* __restrict__ b_p,
                       u16* __restrict__ W2, float* __restrict__ bias2,
                       u16* __restrict__ WA2, float* __restrict__ biasA2,
                       u16* __restrict__ WP, float* __restrict__ biasP,
                       unsigned int* __restrict__ WCV) {
  int i = blockIdx.x * 256 + threadIdx.x;
  if (i < 30720) {                       // W2: 320*96
    int r = i / 96, ci = i % 96;
    float val = 0.f;
    if (r < 192) { int src = (r & 1) ? (96 + (r >> 1)) : (r >> 1); val = w_qk[src * 96 + ci]; }
    else if (r < 288) val = w_v[(r - 192) * 96 + ci];
    W2[i] = f2b(val);
  } else if (i < 31040) {                // bias2: 320
    int r = i - 30720; float bv = 0.f;
    if (r < 192) { int src = (r & 1) ? (96 + (r >> 1)) : (r >> 1); bv = b_qk[src]; }
    else if (r < 288) bv = b_v[r - 192];
    bias2[r] = bv;
  } else if (i < 61760) {                // WA2: 320*96
    int j = i - 31040; int r = j / 96, ci = j % 96;
    float wv = 0.f;
    if (r < 294) wv = w_a2[r * 96 + ci] * g_mul[r];
    WA2[j] = f2b(wv);
  } else if (i < 62080) {                // biasA2: 320
    int r = i - 61760; float bv = 0.f;
    if (r < 294) bv = b_a2[r] * g_mul[r] + g_add[r];
    biasA2[r] = bv;
  } else if (i < 74368) {                // WP: 128*96
    int j = i - 62080; int r = j / 96;
    WP[j] = (r < 96) ? f2b(w_p[j]) : (u16)0;
  } else if (i < 74496) {                // biasP: 128
    int r = i - 74368;
    biasP[r] = (r < 96) ? b_p[r] : 0.f;
  } else if (i < 93312) {                // WCV: dup f16 [g][ch][ky][co][kx], 18816 uints
    int j = i - 74496;
    int kx = j % 7, co = (j / 7) & 3, ky = (j / 28) % 7, ch = (j / 196) & 3, g = j / 784;
    float w = w_a1[(g * 4 + co) * 196 + ch * 49 + ky * 7 + kx];
    unsigned int hw = f2h(w);
    WCV[j] = hw | (hw << 16);
  }
}

// ---------------- MFMA GEMM (64p x all-cout, K=96, cot loop in-block) --------
// MODE 0: fused LayerNorm staging from x f32; writes h f16 (out0) + v f16 (out1).
// MODE 1: X = a_t BLOCKED-4 gather; attn chunk -> out0 f16, f = fArg + blockIdx.y.
// MODE 2: X = out_t BLOCKED-4 bf16; final f32 out (outF=d_out) + resid.
template <int MODE>
__global__ __launch_bounds__(256) void k_gemm(const u16* __restrict__ X,
                                              const u16* __restrict__ W,
                                              const float* __restrict__ bias,
                                              u16* __restrict__ out0,
                                              u16* __restrict__ out1,
                                              float* __restrict__ outF,
                                              const float* __restrict__ resid,
                                              const float* __restrict__ lg,
                                              const float* __restrict__ lb,
                                              int fArg) {
  constexpr int NC = (MODE == 2) ? 2 : 5;
  __shared__ u16 lw[64 * 104];
  __shared__ u16 lx[64 * 104];
  const int tid = threadIdx.x;
  const int fc = blockIdx.y;
  const int f = (MODE == 1) ? (fArg + fc) : fc;
  const int p0 = blockIdx.x * 64;

  if constexpr (MODE == 0) {
    // Fused LayerNorm: thread (pix = tid>>2, sub = tid&3) loads 24 channels of
    // its pixel from x f32, reduces mean/var via 4-lane shfl_xor, writes
    // normalized bf16 into lx.
    const int pix = tid >> 2, sub = tid & 3;
    const int b = f >> 3, d = f & 7;
    const size_t xbase = ((size_t)(b * 768 + d)) * PIX + p0 + pix;
    float xv[24];
    #pragma unroll
    for (int k = 0; k < 24; ++k)
      xv[k] = resid[xbase + (size_t)(sub * 24 + k) * 73728];
    float s = 0.f, ss = 0.f;
    #pragma unroll
    for (int k = 0; k < 24; ++k) { s += xv[k]; ss += xv[k] * xv[k]; }
    s += __shfl_xor(s, 1);  ss += __shfl_xor(ss, 1);
    s += __shfl_xor(s, 2);  ss += __shfl_xor(ss, 2);
    float mu = s * (1.f / 96.f);
    float var = ss * (1.f / 96.f) - mu * mu;
    float rs = rsqrtf(var + 1e-5f);
    unsigned int* dst = (unsigned int*)&lx[pix * 104 + sub * 24];
    #pragma unroll
    for (int k = 0; k < 12; ++k) {
      int c = sub * 24 + 2 * k;
      u16 lo = f2b((xv[2 * k]     - mu) * rs * lg[c]     + lb[c]);
      u16 hi = f2b((xv[2 * k + 1] - mu) * rs * lg[c + 1] + lb[c + 1]);
      dst[k] = (unsigned int)lo | ((unsigned int)hi << 16);
    }
  } else {
    // X is blocked-4: X[((f*24 + g)*PIX + p)*4 + co].
    for (int idx = tid; idx < 768; idx += 256) {
      int s2 = idx >> 6, r = idx & 63;
      const u16* src0 = &X[((size_t)(f * 24 + 2 * s2) * PIX + p0 + r) * 4];
      const u16* src1 = &X[((size_t)(f * 24 + 2 * s2 + 1) * PIX + p0 + r) * 4];
      *(uint2v*)&lx[r * 104 + s2 * 8]     = *(const uint2v*)src0;
      *(uint2v*)&lx[r * 104 + s2 * 8 + 4] = *(const uint2v*)src1;
    }
  }
  __syncthreads();

  const int lane = tid & 63, wv = tid >> 6;
  const int cw = (wv >> 1) * 32, pw = (wv & 1) * 32;
  const int m = lane & 15, quad = lane >> 4;

  for (int cot = 0; cot < NC; ++cot) {
    for (int ch = tid; ch < 768; ch += 256) {
      int r = ch / 12, s2 = ch % 12;
      *(uint4v*)&lw[r * 104 + s2 * 8] =
          *(const uint4v*)&W[(size_t)(cot * 64 + r) * 96 + s2 * 8];
    }
    __syncthreads();

    floatx4 acc[2][2] = {};
    for (int ks = 0; ks < 3; ++ks) {
      int ko = ks * 32 + quad * 8;
      bf16x8 a0 = *(const bf16x8*)&lw[(cw + m) * 104 + ko];
      bf16x8 a1 = *(const bf16x8*)&lw[(cw + 16 + m) * 104 + ko];
      bf16x8 b0 = *(const bf16x8*)&lx[(pw + m) * 104 + ko];
      bf16x8 b1 = *(const bf16x8*)&lx[(pw + 16 + m) * 104 + ko];
      acc[0][0] = __builtin_amdgcn_mfma_f32_16x16x32_bf16(a0, b0, acc[0][0], 0, 0, 0);
      acc[0][1] = __builtin_amdgcn_mfma_f32_16x16x32_bf16(a0, b1, acc[0][1], 0, 0, 0);
      acc[1][0] = __builtin_amdgcn_mfma_f32_16x16x32_bf16(a1, b0, acc[1][0], 0, 0, 0);
      acc[1][1] = __builtin_amdgcn_mfma_f32_16x16x32_bf16(a1, b1, acc[1][1], 0, 0, 0);
    }

    for (int mt = 0; mt < 2; ++mt)
      for (int nt = 0; nt < 2; ++nt) {
        int R = cot * 64 + cw + mt * 16 + quad * 4;
        int pc = p0 + pw + nt * 16 + m;
        floatx4 v4 = acc[mt][nt];
        if (MODE == 0) {
          if (cot < 3) {
            float q0 = v4[0] + bias[R + 0], k0 = v4[1] + bias[R + 1];
            float q1 = v4[2] + bias[R + 2], k1 = v4[3] + bias[R + 3];
            int hc = R >> 1;
            out0[((size_t)f * 96 + hc) * PIX + pc]     = f2h(q0 * k0 * SCALE_QK);
            out0[((size_t)f * 96 + hc + 1) * PIX + pc] = f2h(q1 * k1 * SCALE_QK);
          } else {
            for (int r = 0; r < 4; ++r) {
              int vr = R + r - 192;
              if (vr < 96) out1[((size_t)f * 96 + vr) * PIX + pc] = f2h(v4[r] + bias[R + r]);
            }
          }
        } else if (MODE == 1) {
          for (int r = 0; r < 4; ++r) {
            int o = R + r;
            if (o < 294) out0[((size_t)fc * 294 + o) * PIX + pc] = f2h(v4[r] + bias[o]);
          }
        } else {
          int b = f >> 3, dd = f & 7;
          for (int r = 0; r < 4; ++r) {
            int o = R + r;
            if (o < 96) {
              size_t gi = ((size_t)(b * 96 + o) * 8 + dd) * PIX + pc;
              outF[gi] = resid[gi] + v4[r] + bias[o];
            }
          }
        }
      }
    __syncthreads();
  }
}

// ---------------- grouped 7x7 conv + GELU (packed f16 fma, sliding window) ---
// h: (f, 96, 9216) f16 -> a_t BLOCKED-4: a_t[((f*24+g)*PIX + pix)*4 + co].
// Best-measured form (R6, 70.7us). Frozen.
__global__ __launch_bounds__(256, 4) void k_conv(const u16* __restrict__ h,
                                                 const unsigned int* __restrict__ wcv,
                                                 const float* __restrict__ b_a1,
                                                 u16* __restrict__ a_t) {
  __shared__ u16 li[4 * 22 * 104];   // 18.3KB
  const int g = blockIdx.x, ty = blockIdx.y, f = blockIdx.z;
  const int tid = threadIdx.x;
  const int gb = g * 4, y0 = ty * 16;
  for (int idx = tid; idx < 4576; idx += 256) {
    int row = idx / 52;            // ch*22 + rr
    int jd  = idx - row * 52;
    int ch  = row / 22;
    int rr  = row - ch * 22;
    int ay  = y0 - 3 + rr;
    unsigned int val = 0;
    if (jd >= 2 && jd <= 49 && ay >= 0 && ay < 96)
      val = *(const unsigned int*)&h[((size_t)f * 96 + gb + ch) * PIX + ay * 96 + (2 * jd - 4)];
    *(unsigned int*)&li[row * 104 + 2 * jd] = val;
  }
  __syncthreads();

  const int y = tid >> 4;            // 0..15
  const int x0 = (tid & 15) * 6;     // 0..90 (even)
  f16x2 pacc[4][3];
  #pragma unroll
  for (int co = 0; co < 4; ++co)
    #pragma unroll
    for (int p = 0; p < 3; ++p) pacc[co][p] = upk(0u);

  for (int ch = 0; ch < 4; ++ch) {
    const unsigned int* wch = &wcv[784 * g + 196 * ch];
    for (int ky = 0; ky < 7; ++ky) {
      const unsigned int* lsrc =
          (const unsigned int*)&li[(ch * 22 + (y + ky)) * 104 + x0];
      unsigned int D0 = lsrc[0], D1 = lsrc[1], D2 = lsrc[2], D3 = lsrc[3];
      unsigned int D4 = lsrc[4], D5 = lsrc[5], D6 = lsrc[6];
      unsigned int S0 = __builtin_amdgcn_alignbit(D1, D0, 16);
      unsigned int S1 = __builtin_amdgcn_alignbit(D2, D1, 16);
      unsigned int S2 = __builtin_amdgcn_alignbit(D3, D2, 16);
      unsigned int S3 = __builtin_amdgcn_alignbit(D4, D3, 16);
      unsigned int S4 = __builtin_amdgcn_alignbit(D5, D4, 16);
      unsigned int S5 = __builtin_amdgcn_alignbit(D6, D5, 16);
      const unsigned int* wb = wch + 28 * ky;
      #pragma unroll
      for (int co = 0; co < 4; ++co) {
        unsigned int w0 = wb[co * 7 + 0], w1 = wb[co * 7 + 1];
        unsigned int w2 = wb[co * 7 + 2], w3 = wb[co * 7 + 3];
        unsigned int w4 = wb[co * 7 + 4], w5 = wb[co * 7 + 5];
        unsigned int w6 = wb[co * 7 + 6];
        f16x2 a;
        a = pacc[co][0];
        a = pkfma(w0, S0, a); a = pkfma(w1, D1, a); a = pkfma(w2, S1, a);
        a = pkfma(w3, D2, a); a = pkfma(w4, S2, a); a = pkfma(w5, D3, a);
        a = pkfma(w6, S3, a); pacc[co][0] = a;
        a = pacc[co][1];
        a = pkfma(w0, S1, a); a = pkfma(w1, D2, a); a = pkfma(w2, S2, a);
        a = pkfma(w3, D3, a); a = pkfma(w4, S3, a); a = pkfma(w5, D4, a);
        a = pkfma(w6, S4, a); pacc[co][1] = a;
        a = pacc[co][2];
        a = pkfma(w0, S2, a); a = pkfma(w1, D3, a); a = pkfma(w2, S3, a);
        a = pkfma(w3, D4, a); a = pkfma(w4, S4, a); a = pkfma(w5, D5, a);
        a = pkfma(w6, S5, a); pacc[co][2] = a;
      }
    }
  }

  size_t obase = ((size_t)(f * 24 + g) * PIX + (size_t)(y0 + y) * 96 + x0) * 4;
  float bv0 = b_a1[gb + 0], bv1 = b_a1[gb + 1], bv2 = b_a1[gb + 2], bv3 = b_a1[gb + 3];
  #pragma unroll
  for (int p = 0; p < 3; ++p) {
    ushort8 r8;
    #pragma unroll
    for (int co = 0; co < 4; ++co) {
      float bv = (co == 0) ? bv0 : (co == 1) ? bv1 : (co == 2) ? bv2 : bv3;
      f16x2 v = pacc[co][p];
      float a0 = (float)v[0] + bv, a1 = (float)v[1] + bv;
      r8[co]     = f2b(0.5f * a0 * (1.f + erff(a0 * 0.70710678118f)));
      r8[co + 4] = f2b(0.5f * a1 * (1.f + erff(a1 * 0.70710678118f)));
    }
    *(ushort8*)&a_t[obase + p * 8] = r8;
  }
}

// ---------------- 49-tap window aggregation (8-frame chunk, packed f16) ------
// attn_c: (8, 294, 9216) f16, v: (f, 96, 9216) f16 -> out_t BLOCKED-4 bf16.
// Packed-pair core: attn dword = (attn[x],attn[x+1]) used directly as operand;
// v pairs from D/S alignbit pattern (same as conv). Zero unpacks in inner loop.
// XCD swizzle: 4 cquads sharing one head's attn planes co-resident on one XCD.
__global__ __launch_bounds__(256, 4) void k_aggr(const u16* __restrict__ attn_c,
                                                 const u16* __restrict__ v,
                                                 u16* __restrict__ out_t,
                                                 int fbase) {
  __shared__ u16 lv[4 * 22 * 104];   // 18.3KB, col = ax+4 (left pad 4)
  const int wgid = blockIdx.x + 24 * (blockIdx.y + 6 * blockIdx.z);
  const int xcd = wgid & 7;
  const int member = (wgid >> 3) & 3;
  const int slot = wgid >> 5;
  const int gidx = slot * 8 + xcd;       // 0..287
  const int cqh = gidx % 6;
  const int ty = (gidx / 6) % 6;
  const int fc = gidx / 36;
  const int cq = cqh * 4 + member;
  const int f = fbase + fc;
  const int tid = threadIdx.x;
  const int c0 = cq * 4, y0 = ty * 16;
  const int head = c0 >> 4;
  // dword staging (conv pattern): 4ch x 22 rows x 52 dwords; jd covers ax=2jd-4,2jd-3.
  for (int idx = tid; idx < 4576; idx += 256) {
    int row = idx / 52;            // ch*22 + rr
    int jd  = idx - row * 52;
    int ch  = row / 22;
    int rr  = row - ch * 22;
    int ay  = y0 - 3 + rr;
    unsigned int val = 0;
    if (jd >= 2 && jd <= 49 && ay >= 0 && ay < 96)
      val = *(const unsigned int*)&v[((size_t)f * 96 + c0 + ch) * PIX + ay * 96 + (2 * jd - 4)];
    *(unsigned int*)&lv[row * 104 + 2 * jd] = val;
  }
  __syncthreads();

  const int y = tid >> 4;            // 0..15
  const int x0 = (tid & 15) * 6;     // 0..90 (even)
  const int prow = (y0 + y) * 96 + x0;
  f16x2 pacc[4][3];
  #pragma unroll
  for (int ch = 0; ch < 4; ++ch)
    #pragma unroll
    for (int t = 0; t < 3; ++t) pacc[ch][t] = upk(0u);

  for (int i = 0; i < 7; ++i) {
    // v row windows: D0..D6 dwords (cols x0..x0+13), S = 1-elem shifted pairs.
    unsigned int vD[4][7], vS[4][6];
    #pragma unroll
    for (int ch = 0; ch < 4; ++ch) {
      const unsigned int* lsrc = (const unsigned int*)&lv[(ch * 22 + (y + i)) * 104 + x0];
      #pragma unroll
      for (int t = 0; t < 7; ++t) vD[ch][t] = lsrc[t];
      #pragma unroll
      for (int t = 0; t < 6; ++t)
        vS[ch][t] = __builtin_amdgcn_alignbit(vD[ch][t + 1], vD[ch][t], 16);
    }
    #pragma unroll
    for (int j = 0; j < 7; ++j) {
      const unsigned int* asrc = (const unsigned int*)
          &attn_c[((size_t)fc * 294 + head * 49 + i * 7 + j) * PIX + prow];
      unsigned int a0 = asrc[0], a1 = asrc[1], a2 = asrc[2];
      // output pair t (px x0+2t, x0+2t+1), tap j: v pair at ax0 = x0+2t+j-3
      //   j even -> vS[t + j/2] ; j odd -> vD[t + (j+1)/2]
      #pragma unroll
      for (int ch = 0; ch < 4; ++ch) {
        unsigned int p0v, p1v, p2v;
        if (j & 1) { p0v = vD[ch][(j + 1) / 2];     p1v = vD[ch][1 + (j + 1) / 2];
                     p2v = vD[ch][2 + (j + 1) / 2]; }
        else       { p0v = vS[ch][j / 2];           p1v = vS[ch][1 + j / 2];
                     p2v = vS[ch][2 + j / 2]; }
        pacc[ch][0] = pkfma(a0, p0v, pacc[ch][0]);
        pacc[ch][1] = pkfma(a1, p1v, pacc[ch][1]);
        pacc[ch][2] = pkfma(a2, p2v, pacc[ch][2]);
      }
    }
  }

  // blocked-4 store: 48B contiguous per thread (out_t stays bf16 for gemm2 MFMA).
  size_t obase = ((size_t)(f * 24 + cq) * PIX + prow) * 4;
  #pragma unroll
  for (int t = 0; t < 3; ++t) {
    ushort8 r8;
    #pragma unroll
    for (int ch = 0; ch < 4; ++ch) {
      f16x2 pv = pacc[ch][t];
      r8[ch]     = f2b((float)pv[0]);
      r8[ch + 4] = f2b((float)pv[1]);
    }
    *(ushort8*)&out_t[obase + t * 8] = r8;
  }
}

extern "C" void kernel_launch(void* const* d_in, const int* in_sizes, int n_in,
                              void* d_out, int out_size, void* d_ws, size_t ws_size,
                              hipStream_t stream) {
  const float* x    = (const float*)d_in[0];
  const float* ln_g = (const float*)d_in[1];
  const float* ln_b = (const float*)d_in[2];
  const float* w_qk = (const float*)d_in[3];
  const float* b_qk = (const float*)d_in[4];
  const float* w_v  = (const float*)d_in[5];
  const float* b_v  = (const float*)d_in[6];
  const float* w_a1 = (const float*)d_in[7];
  const float* b_a1 = (const float*)d_in[8];
  const float* w_a2 = (const float*)d_in[9];
  const float* b_a2 = (const float*)d_in[10];
  const float* g_mul= (const float*)d_in[11];
  const float* g_add= (const float*)d_in[12];
  const float* w_p  = (const float*)d_in[13];
  const float* b_p  = (const float*)d_in[14];

  char* ws = (char*)d_ws;
  u16*   W2    = (u16*)(ws + 0);
  float* bias2 = (float*)(ws + 61440);
  u16*   WA2   = (u16*)(ws + 62720);
  float* biasA2= (float*)(ws + 124160);
  u16*   WP    = (u16*)(ws + 125440);
  float* biasP = (float*)(ws + 150016);
  unsigned int* WCV = (unsigned int*)(ws + 150528);
  u16*   a_t   = (u16*)(ws + 225792);
  u16*   hbuf  = (u16*)(ws + 28537344);     // reused as out_t
  u16*   vbuf  = (u16*)(ws + 56848896);
  u16*   attnc = (u16*)(ws + 85160448);     // 8-frame attn chunk (8 x 294 x 9216)

  k_prep<<<365, 256, 0, stream>>>(w_qk, b_qk, w_v, b_v, w_a1, w_a2, b_a2, g_mul, g_add,
                                  w_p, b_p, W2, bias2, WA2, biasA2, WP, biasP, WCV);
  k_gemm<0><<<dim3(144, 16), 256, 0, stream>>>(nullptr, W2, bias2, hbuf, vbuf,
                                               nullptr, x, ln_g, ln_b, 0);
  k_conv<<<dim3(24, 6, 16), 256, 0, stream>>>(hbuf, WCV, b_a1, a_t);
  for (int c = 0; c < 2; ++c) {
    k_gemm<1><<<dim3(144, 8), 256, 0, stream>>>(a_t, WA2, biasA2,
                                                attnc, nullptr, nullptr, nullptr,
                                                nullptr, nullptr, c * 8);
    k_aggr<<<dim3(24, 6, 8), 256, 0, stream>>>(attnc, vbuf, hbuf /*out_t*/, c * 8);
  }
  k_gemm<2><<<dim3(144, 16), 256, 0, stream>>>(hbuf /*out_t*/, WP, biasP,
                                               nullptr, nullptr, (float*)d_out, x,
                                               nullptr, nullptr, 0);
}